// Round 16
// baseline (237.543 us; speedup 1.0000x reference)
//
#include <hip/hip_runtime.h>

// R16: R13 (best, 158.4) + readout folded into gnn3 via completion-rank
// counter: each gnn3 block fetch_adds cnt after its gsum atomics; the last 16
// finishers (rank>=1008) each run one batch's readout in-block (brief spin to
// rank 1024 -- only 16 waves poll, no R10-style coherence storm). Saves the
// readout launch + dispatch gap. Everything else R13 verbatim.
// Intermediates FEATURE-MAJOR h[b][f][n], n = 64x64 grid.
// GNN layer exact rewrite: h' = relu( agg(h) @ W + rowsum*b ).
// fp32 split a = hi + lo (bf16); 3 MFMAs: hi*wh + hi*wl + lo*wh.
//
// MFMA 16x16x32 bf16 layouts (verified m89/m120):
//   A (MxK): m = lane&15, k = quad*8 + j    B (KxN): n = lane&15, k = quad*8 + j
//   C/D: col(N) = lane&15, row(M) = quad*4 + reg

typedef __attribute__((ext_vector_type(8))) short bf16x8;
typedef __attribute__((ext_vector_type(4))) float f32x4;
#define MFMA(a, b, c) __builtin_amdgcn_mfma_f32_16x16x32_bf16(a, b, c, 0, 0, 0)

// barrier with LDS visibility but WITHOUT draining global loads:
// s_waitcnt imm 0xC07F = vmcnt(63) expcnt(7) lgkmcnt(0)
__device__ inline void block_sync_lgkm() {
    asm volatile("" ::: "memory");
    __builtin_amdgcn_s_waitcnt(0xC07F);
    __builtin_amdgcn_s_barrier();
    asm volatile("" ::: "memory");
}

__device__ inline ushort bf16h(float x) {
    unsigned u = __float_as_uint(x);
    return (ushort)((u + 0x7fffu + ((u >> 16) & 1u)) >> 16);
}
__device__ inline void split_bf16(float x, ushort& hi, ushort& lo) {
    hi = bf16h(x);
    lo = bf16h(x - __uint_as_float(((unsigned)hi) << 16));
}
// packed (hi16 << 16) | lo16 ; hi = RNE, lo = truncation
__device__ inline unsigned pack_split(float x) {
    unsigned u = __float_as_uint(x);
    unsigned hi = (u + 0x7fffu + ((u >> 16) & 1u)) >> 16;
    float r = x - __uint_as_float(hi << 16);
    return (hi << 16) | (__float_as_uint(r) >> 16);
}
// 8 packed u32 (stride 65) -> hi/lo bf16x8 fragments
__device__ inline void frag_packed(const unsigned* bp, bf16x8& bh, bf16x8& bl) {
    unsigned p[8];
#pragma unroll
    for (int j = 0; j < 8; j++) p[j] = bp[j * 65];
    union { bf16x8 v; unsigned d[4]; } H, L;
#pragma unroll
    for (int j = 0; j < 4; j++) {
        const unsigned e = p[2 * j], o = p[2 * j + 1];
        H.d[j] = (o & 0xFFFF0000u) | (e >> 16);
        L.d[j] = (o << 16) | (e & 0xFFFFu);
    }
    bh = H.v; bl = L.v;
}

// ---- fused launch 1: g-weight prep (blk<20) + gsum/cnt zero (blk<28) + embed ----
__global__ __launch_bounds__(256, 4) void prep_embed_kernel(
    const float* __restrict__ obs,
    const float* __restrict__ e1w, const float* __restrict__ e1b,
    const float* __restrict__ e2w, const float* __restrict__ e2b,
    const float* __restrict__ g1w, const float* __restrict__ g2w,
    const float* __restrict__ g3w, ushort* __restrict__ wf,
    float* __restrict__ gsum, unsigned* __restrict__ cnt,
    float* __restrict__ h0)
{
    const int blk = blockIdx.x, tid = threadIdx.x;

    if (blk < 20) {                        // ---- g-weight prep: 4 units/block ----
        const int u = blk * 4 + (tid >> 6);
        const int l = tid & 63;
        const float* src; int K, kc, t; ushort* dst;
        if (u < 16)      { src = g1w; K = 64;  kc = u >> 3;        t = u & 7; dst = wf + 12288; }
        else if (u < 48) { src = g2w; K = 128; kc = (u - 16) >> 3; t = (u - 16) & 7; dst = wf + 28672; }
        else             { src = g3w; K = 128; kc = (u - 48) >> 3; t = (u - 48) & 7; dst = wf + 61440; }
        ushort* uh = dst + ((kc * 8 + t) * 2 + 0) * 512 + l * 8;
        ushort* ul = dst + ((kc * 8 + t) * 2 + 1) * 512 + l * 8;
        const int f = t * 16 + (l & 15);
        const int kb = kc * 32 + ((l >> 4) << 3);
#pragma unroll
        for (int j = 0; j < 8; j++) {
            const int k = kb + j;
            const float w = (k < K) ? src[k * 128 + f] : 0.f;
            ushort hi, lo; split_bf16(w, hi, lo);
            uh[j] = hi; ul[j] = lo;
        }
        return;
    }
    if (blk < 28) {                        // ---- zero gsum + completion counter ----
        gsum[(blk - 20) * 256 + tid] = 0.f;
        if (blk == 27 && tid == 0)
            __hip_atomic_store(cnt, 0u, __ATOMIC_RELAXED, __HIP_MEMORY_SCOPE_AGENT);
        return;
    }

    // ---- embed: block = (b, row) = 64 nodes, fused 2-layer MLP via MFMA ----
    __shared__ unsigned lds[6240];
    const int eb = blk - 28;
    const int ebid = ((eb & 7) << 7) | (eb >> 3);   // XCD remap aligned w/ gnn readers
    const int b = ebid >> 6, row = ebid & 63;
    const int lane = tid & 63, w = tid >> 6, quad = lane >> 4, nl = lane & 15;
    const int cp = tid >> 4, nq = tid & 15;

    const float4 x4 = *(const float4*)(obs + ((size_t)(b * 16 + cp) << 12) + row * 64 + nq * 4);

    {
        float* wr = (float*)lds;
#pragma unroll
        for (int i = 0; i < 20; i++) {
            const int idx = tid + 256 * i;
            wr[idx] = (idx < 1024) ? e1w[idx] : e2w[idx - 1024];
        }
    }
    __syncthreads();

    bf16x8 e1h, e1l, e2h[2], e2l[2];
    {
        const float* wr = (const float*)lds;
        const int f = 16 * w + nl;
#pragma unroll
        for (int j = 0; j < 8; j++) {
            const int k = quad * 8 + j;
            const float v = (k < 16) ? wr[k * 64 + f] : 0.f;
            ushort hi, lo; split_bf16(v, hi, lo);
            e1h[j] = (short)hi; e1l[j] = (short)lo;
        }
#pragma unroll
        for (int kc = 0; kc < 2; kc++)
#pragma unroll
            for (int j = 0; j < 8; j++) {
                const int k = kc * 32 + quad * 8 + j;
                const float v = wr[1024 + k * 64 + f];
                ushort hi, lo; split_bf16(v, hi, lo);
                e2h[kc][j] = (short)hi; e2l[kc][j] = (short)lo;
            }
    }
    __syncthreads();

    unsigned* Xs = lds;
    unsigned* Hs = lds + 2080;
    {
        unsigned* xp = Xs + cp * 65 + nq * 4;
        xp[0] = pack_split(x4.x); xp[1] = pack_split(x4.y);
        xp[2] = pack_split(x4.z); xp[3] = pack_split(x4.w);
        unsigned* zp = Xs + (16 + cp) * 65 + nq * 4;
        zp[0] = 0u; zp[1] = 0u; zp[2] = 0u; zp[3] = 0u;
    }
    __syncthreads();

#pragma unroll
    for (int nt = 0; nt < 4; nt++) {
        const unsigned* bp = Xs + (quad * 8) * 65 + nt * 16 + nl;
        bf16x8 bh, bl; frag_packed(bp, bh, bl);
        f32x4 c = {0.f, 0.f, 0.f, 0.f};
        c = MFMA(e1h, bh, c); c = MFMA(e1h, bl, c); c = MFMA(e1l, bh, c);
#pragma unroll
        for (int reg = 0; reg < 4; reg++) {
            const int fm = 16 * w + quad * 4 + reg;
            Hs[fm * 65 + nt * 16 + nl] = pack_split(fmaxf(c[reg] + e1b[fm], 0.f));
        }
    }
    __syncthreads();

    f32x4 a2[4];
#pragma unroll
    for (int nt = 0; nt < 4; nt++) a2[nt] = (f32x4){0.f, 0.f, 0.f, 0.f};
#pragma unroll
    for (int kc = 0; kc < 2; kc++) {
#pragma unroll
        for (int nt = 0; nt < 4; nt++) {
            const unsigned* bp = Hs + (kc * 32 + quad * 8) * 65 + nt * 16 + nl;
            bf16x8 bh, bl; frag_packed(bp, bh, bl);
            a2[nt] = MFMA(e2h[kc], bh, a2[nt]);
            a2[nt] = MFMA(e2h[kc], bl, a2[nt]);
            a2[nt] = MFMA(e2l[kc], bh, a2[nt]);
        }
    }
#pragma unroll
    for (int reg = 0; reg < 4; reg++) {
        const int f = 16 * w + quad * 4 + reg;
        const float bv = e2b[f];
#pragma unroll
        for (int nt = 0; nt < 4; nt++)
            h0[((size_t)(b * 64 + f) << 12) + row * 64 + nt * 16 + nl] =
                fmaxf(a2[nt][reg] + bv, 0.f);
    }
}

// ---- GNN layer: quarter-pipelined (R13); MEAN also runs fused readout ----
template <int K, bool MEAN>
__global__ __launch_bounds__(256, 4) void gnn_kernel(
    const float* __restrict__ hin, const ushort* __restrict__ wf,
    const float* __restrict__ bias, float* __restrict__ hout,
    float* __restrict__ gsum, unsigned* __restrict__ cnt,
    const float* __restrict__ r1w, const float* __restrict__ r1b,
    const float* __restrict__ r2w, const float* __restrict__ r2b,
    float* __restrict__ out)
{
    constexpr int NQ = K / 32;
    __shared__ unsigned As[2][32 * 65];
    const int tid = threadIdx.x;
    // XCD-contiguous remap: consecutive rows on the same XCD (R7: FETCH 49->18MB)
    const int bid = ((blockIdx.x & 7) << 7) | (blockIdx.x >> 3);
    const int b = bid >> 6, row = bid & 63;
    const int lane = tid & 63, w = tid >> 6, quad = lane >> 4, nl = lane & 15;
    const int kp = tid >> 4, nq = tid & 15;
    const float* hb = hin + (size_t)b * K * 4096;
    const int rowu = (row > 0) ? row - 1 : row;
    const int rowd = (row < 63) ? row + 1 : row;
    const float su = (row > 0) ? 1.f : 0.f;
    const float sd = (row < 63) ? 1.f : 0.f;
    float inv[4];
#pragma unroll
    for (int i = 0; i < 4; i++) {
        const int n = nq * 4 + i;
        const int deg = (row > 0) + (row < 63) + (n > 0) + (n < 63);
        inv[i] = 1.f / ((float)deg + 1e-6f);
    }

    const ushort* wfl = wf + lane * 8;
    f32x4 acc[4][2];
#pragma unroll
    for (int nt = 0; nt < 4; nt++) {
        acc[nt][0] = (f32x4){0.f, 0.f, 0.f, 0.f};
        acc[nt][1] = (f32x4){0.f, 0.f, 0.f, 0.f};
    }

    float4 S[6];          // ONE staging register set (24 VGPR)
    bf16x8 V[2][2];       // current quarter's weights [ftl][hi/lo]

    auto sload = [&](int q) {
#pragma unroll
        for (int it = 0; it < 2; it++) {
            const int kg = q * 32 + it * 16 + kp;
            const float* pk = hb + ((size_t)kg << 12) + nq * 4;
            S[it * 3 + 0] = *(const float4*)(pk + row * 64);
            S[it * 3 + 1] = *(const float4*)(pk + rowu * 64);
            S[it * 3 + 2] = *(const float4*)(pk + rowd * 64);
        }
    };
    auto wload = [&](int q) {
#pragma unroll
        for (int ftl = 0; ftl < 2; ftl++) {
            V[ftl][0] = *(const bf16x8*)(wfl + ((q * 8 + 2 * w + ftl) * 2) * 512);
            V[ftl][1] = *(const bf16x8*)(wfl + ((q * 8 + 2 * w + ftl) * 2 + 1) * 512);
        }
    };
    auto stage = [&](unsigned* Ab) {
#pragma unroll
        for (int it = 0; it < 2; it++) {
            const int kl = it * 16 + kp;
            const float4 c4 = S[it * 3 + 0];
            const float4 u4 = S[it * 3 + 1];
            const float4 d4 = S[it * 3 + 2];
            const float pw = __shfl_up(c4.w, 1);
            const float nx = __shfl_down(c4.x, 1);
            const float lx = (nq > 0) ? pw : 0.f;
            const float rw = (nq < 15) ? nx : 0.f;
            unsigned* ap = Ab + kl * 65 + nq * 4;
            ap[0] = pack_split((su * u4.x + sd * d4.x + lx + c4.y) * inv[0]);
            ap[1] = pack_split((su * u4.y + sd * d4.y + c4.x + c4.z) * inv[1]);
            ap[2] = pack_split((su * u4.z + sd * d4.z + c4.y + c4.w) * inv[2]);
            ap[3] = pack_split((su * u4.w + sd * d4.w + c4.z + rw) * inv[3]);
        }
    };
    auto consume = [&](const unsigned* Ab) {
#pragma unroll
        for (int nt = 0; nt < 4; nt++) {
            const unsigned* bp = Ab + (quad * 8) * 65 + nt * 16 + nl;
            bf16x8 bh, bl; frag_packed(bp, bh, bl);
            acc[nt][0] = MFMA(V[0][0], bh, acc[nt][0]);
            acc[nt][0] = MFMA(V[0][0], bl, acc[nt][0]);
            acc[nt][0] = MFMA(V[0][1], bh, acc[nt][0]);
            acc[nt][1] = MFMA(V[1][0], bh, acc[nt][1]);
            acc[nt][1] = MFMA(V[1][0], bl, acc[nt][1]);
            acc[nt][1] = MFMA(V[1][1], bh, acc[nt][1]);
        }
    };

    // prologue
    wload(0);
    sload(0);
    stage(As[0]);
    sload(1);
    block_sync_lgkm();

#pragma unroll
    for (int q = 0; q < NQ; q++) {
        consume(As[q & 1]);                    // waits V(q): vmcnt<=6, no drain
        if (q + 1 < NQ) {
            wload(q + 1);
            stage(As[(q + 1) & 1]);            // waits S(q+1): vmcnt<=4
            if (q + 2 < NQ) sload(q + 2);      // S regs free after stage
            block_sync_lgkm();                 // globals stay in flight
        }
    }

    // ---- epilogue ----
    if (!MEAN) {
#pragma unroll
        for (int ftl = 0; ftl < 2; ftl++) {
            const int fb = 32 * w + 16 * ftl + quad * 4;
            const float b0 = bias[fb], b1 = bias[fb + 1], b2 = bias[fb + 2], b3 = bias[fb + 3];
#pragma unroll
            for (int nt = 0; nt < 4; nt++) {
                const int n = 16 * nt + nl;
                const int deg = (row > 0) + (row < 63) + (n > 0) + (n < 63);
                const float rs = (float)deg / ((float)deg + 1e-6f);
                float* op = hout + ((size_t)(b * 128 + fb) << 12) + row * 64 + n;
                op[0]        = fmaxf(acc[nt][ftl][0] + rs * b0, 0.f);
                op[1u << 12] = fmaxf(acc[nt][ftl][1] + rs * b1, 0.f);
                op[2u << 12] = fmaxf(acc[nt][ftl][2] + rs * b2, 0.f);
                op[3u << 12] = fmaxf(acc[nt][ftl][3] + rs * b3, 0.f);
            }
        }
    } else {
#pragma unroll
        for (int ftl = 0; ftl < 2; ftl++) {
            const int fb = 32 * w + 16 * ftl + quad * 4;
#pragma unroll
            for (int reg = 0; reg < 4; reg++) {
                const float bv = bias[fb + reg];
                float v = 0.f;
#pragma unroll
                for (int nt = 0; nt < 4; nt++) {
                    const int n = 16 * nt + nl;
                    const int deg = (row > 0) + (row < 63) + (n > 0) + (n < 63);
                    const float rs = (float)deg / ((float)deg + 1e-6f);
                    v += fmaxf(acc[nt][ftl][reg] + rs * bv, 0.f);
                }
                v += __shfl_xor(v, 1); v += __shfl_xor(v, 2);
                v += __shfl_xor(v, 4); v += __shfl_xor(v, 8);
                if (nl == 0) atomicAdd(&gsum[b * 128 + fb + reg], v * (1.f / 4096.f));
            }
        }

        // ---- fused readout: last 16 finishers each handle one batch ----
        __shared__ unsigned rank_s;
        __threadfence();                       // order gsum atomics before cnt RMW
        __syncthreads();
        if (tid == 0)
            rank_s = __hip_atomic_fetch_add(cnt, 1u, __ATOMIC_ACQ_REL, __HIP_MEMORY_SCOPE_AGENT);
        __syncthreads();
        const unsigned rank = rank_s;
        if (rank >= 1008u) {
            if (tid == 0) {
                while (__hip_atomic_load(cnt, __ATOMIC_ACQUIRE, __HIP_MEMORY_SCOPE_AGENT) < 1024u)
                    __builtin_amdgcn_s_sleep(8);
            }
            __syncthreads();
            __threadfence();
            const int rb = (int)(rank - 1008u);     // batch 0..15 (unique)
            float* gs = (float*)As;                 // reuse LDS
            float* g2 = gs + 128;
            if (tid < 128)
                gs[tid] = __hip_atomic_load(&gsum[rb * 128 + tid],
                                            __ATOMIC_RELAXED, __HIP_MEMORY_SCOPE_AGENT);
            __syncthreads();
            float a = r1b[tid];
#pragma unroll 16
            for (int k = 0; k < 128; k++) a = fmaf(gs[k], r1w[k * 256 + tid], a);
            g2[tid] = fmaxf(a, 0.f);
            __syncthreads();
            float a2 = r2b[tid];
#pragma unroll 16
            for (int k = 0; k < 256; k++) a2 = fmaf(g2[k], r2w[k * 256 + tid], a2);
            out[rb * 256 + tid] = fmaxf(a2, 0.f);
        }
    }
}

extern "C" void kernel_launch(void* const* d_in, const int* in_sizes, int n_in,
                              void* d_out, int out_size, void* d_ws, size_t ws_size,
                              hipStream_t stream)
{
    const float* obs = (const float*)d_in[0];
    const float* e1w = (const float*)d_in[1];
    const float* e1b = (const float*)d_in[2];
    const float* e2w = (const float*)d_in[3];
    const float* e2b = (const float*)d_in[4];
    const float* g1w = (const float*)d_in[5];
    const float* g1b = (const float*)d_in[6];
    const float* g2w = (const float*)d_in[7];
    const float* g2b = (const float*)d_in[8];
    const float* g3w = (const float*)d_in[9];
    const float* g3b = (const float*)d_in[10];
    const float* r1w = (const float*)d_in[11];
    const float* r1b = (const float*)d_in[12];
    const float* r2w = (const float*)d_in[13];
    const float* r2b = (const float*)d_in[14];
    float* out = (float*)d_out;
    float* ws = (float*)d_ws;

    float* h0 = ws;                                   // 16 MB
    float* h1 = ws + 4194304;                         // 32 MB
    float* h2 = ws + 4194304 + 8388608;               // 32 MB
    float* gsum = (float*)((char*)d_ws + 80u * 1024u * 1024u);          // 8 KB
    ushort* wfb = (ushort*)((char*)d_ws + 80u * 1024u * 1024u + 8192u); // 184 KB
    unsigned* cnt = (unsigned*)((char*)d_ws + 80u * 1024u * 1024u + 200u * 1024u);

    hipLaunchKernelGGL(prep_embed_kernel, dim3(1052), dim3(256), 0, stream,
                       obs, e1w, e1b, e2w, e2b, g1w, g2w, g3w, wfb, gsum, cnt, h0);
    hipLaunchKernelGGL((gnn_kernel<64, false>), dim3(1024), dim3(256), 0, stream,
                       h0, wfb + 12288, g1b, h1, nullptr, nullptr,
                       nullptr, nullptr, nullptr, nullptr, nullptr);
    hipLaunchKernelGGL((gnn_kernel<128, false>), dim3(1024), dim3(256), 0, stream,
                       h1, wfb + 28672, g2b, h2, nullptr, nullptr,
                       nullptr, nullptr, nullptr, nullptr, nullptr);
    hipLaunchKernelGGL((gnn_kernel<128, true>), dim3(1024), dim3(256), 0, stream,
                       h2, wfb + 61440, g3b, nullptr, gsum, cnt,
                       r1w, r1b, r2w, r2b, out);
}

// Round 17
// 158.030 us; speedup vs baseline: 1.5032x; 1.5032x over previous
//
#include <hip/hip_runtime.h>

// R17 = R13 verbatim (empirical optimum, 158.4 us). Sixteen structural
// variants bracket this design; all regressed or were neutral:
//   LDS-throughput fix (R1), SGPR weights (R1), MFMA bf16x3 (R2+), streaming
//   staging (R4), reg batching (R5/R6), global_load_lds (R7), drain-free
//   barriers (R8), launch fusion (R9), mega-kernel (R10: coherence storm),
//   node-split (R11: 256B write amplification), feat-split (R12: read dup),
//   single-barrier K-loop (R14), embed->gnn1 fusion (R15), fused readout
//   (R16: device-scope sync storm). Remaining time = ~46us harness fill +
//   ~112us latency-bound plateau (MfmaUtil ~4%, VALUBusy ~13%, hbm ~30%).
// Intermediates FEATURE-MAJOR h[b][f][n], n = 64x64 grid.
// GNN layer exact rewrite: h' = relu( agg(h) @ W + rowsum*b ).
// fp32 split a = hi + lo (bf16); 3 MFMAs: hi*wh + hi*wl + lo*wh.
//
// MFMA 16x16x32 bf16 layouts (verified m89/m120):
//   A (MxK): m = lane&15, k = quad*8 + j    B (KxN): n = lane&15, k = quad*8 + j
//   C/D: col(N) = lane&15, row(M) = quad*4 + reg

typedef __attribute__((ext_vector_type(8))) short bf16x8;
typedef __attribute__((ext_vector_type(4))) float f32x4;
#define MFMA(a, b, c) __builtin_amdgcn_mfma_f32_16x16x32_bf16(a, b, c, 0, 0, 0)

// barrier with LDS visibility but WITHOUT draining global loads:
// s_waitcnt imm 0xC07F = vmcnt(63) expcnt(7) lgkmcnt(0)
__device__ inline void block_sync_lgkm() {
    asm volatile("" ::: "memory");
    __builtin_amdgcn_s_waitcnt(0xC07F);
    __builtin_amdgcn_s_barrier();
    asm volatile("" ::: "memory");
}

__device__ inline ushort bf16h(float x) {
    unsigned u = __float_as_uint(x);
    return (ushort)((u + 0x7fffu + ((u >> 16) & 1u)) >> 16);
}
__device__ inline void split_bf16(float x, ushort& hi, ushort& lo) {
    hi = bf16h(x);
    lo = bf16h(x - __uint_as_float(((unsigned)hi) << 16));
}
// packed (hi16 << 16) | lo16 ; hi = RNE, lo = truncation
__device__ inline unsigned pack_split(float x) {
    unsigned u = __float_as_uint(x);
    unsigned hi = (u + 0x7fffu + ((u >> 16) & 1u)) >> 16;
    float r = x - __uint_as_float(hi << 16);
    return (hi << 16) | (__float_as_uint(r) >> 16);
}
// 8 packed u32 (stride 65) -> hi/lo bf16x8 fragments
__device__ inline void frag_packed(const unsigned* bp, bf16x8& bh, bf16x8& bl) {
    unsigned p[8];
#pragma unroll
    for (int j = 0; j < 8; j++) p[j] = bp[j * 65];
    union { bf16x8 v; unsigned d[4]; } H, L;
#pragma unroll
    for (int j = 0; j < 4; j++) {
        const unsigned e = p[2 * j], o = p[2 * j + 1];
        H.d[j] = (o & 0xFFFF0000u) | (e >> 16);
        L.d[j] = (o << 16) | (e & 0xFFFFu);
    }
    bh = H.v; bl = L.v;
}

// ---- fused launch 1: g-weight prep (blk<20) + gsum zero (blk<28) + embed ----
// g-frag unit (kc,t) = 2 planes x 512 ushorts; per layer unit idx = kc*8 + t.
// wfb ushort offsets: g1@12288 (16 units), g2@28672 (32), g3@61440 (32).
__global__ __launch_bounds__(256, 4) void prep_embed_kernel(
    const float* __restrict__ obs,
    const float* __restrict__ e1w, const float* __restrict__ e1b,
    const float* __restrict__ e2w, const float* __restrict__ e2b,
    const float* __restrict__ g1w, const float* __restrict__ g2w,
    const float* __restrict__ g3w, ushort* __restrict__ wf,
    float* __restrict__ gsum, float* __restrict__ h0)
{
    const int blk = blockIdx.x, tid = threadIdx.x;

    if (blk < 20) {                        // ---- g-weight prep: 4 units/block ----
        const int u = blk * 4 + (tid >> 6);
        const int l = tid & 63;
        const float* src; int K, kc, t; ushort* dst;
        if (u < 16)      { src = g1w; K = 64;  kc = u >> 3;        t = u & 7; dst = wf + 12288; }
        else if (u < 48) { src = g2w; K = 128; kc = (u - 16) >> 3; t = (u - 16) & 7; dst = wf + 28672; }
        else             { src = g3w; K = 128; kc = (u - 48) >> 3; t = (u - 48) & 7; dst = wf + 61440; }
        ushort* uh = dst + ((kc * 8 + t) * 2 + 0) * 512 + l * 8;
        ushort* ul = dst + ((kc * 8 + t) * 2 + 1) * 512 + l * 8;
        const int f = t * 16 + (l & 15);
        const int kb = kc * 32 + ((l >> 4) << 3);
#pragma unroll
        for (int j = 0; j < 8; j++) {
            const int k = kb + j;
            const float w = (k < K) ? src[k * 128 + f] : 0.f;
            ushort hi, lo; split_bf16(w, hi, lo);
            uh[j] = hi; ul[j] = lo;
        }
        return;
    }
    if (blk < 28) {                        // ---- zero gsum (8 x 256 = 2048) ----
        gsum[(blk - 20) * 256 + tid] = 0.f;
        return;
    }

    // ---- embed: block = (b, row) = 64 nodes, fused 2-layer MLP via MFMA ----
    __shared__ unsigned lds[6240];         // phase W: raw e1w|e2w (5120 f32)
                                           // then Xs = lds[0..2080), Hs = lds+2080
    // XCD remap ALIGNED with gnn readers: h0 rows land on the XCD that reads them
    const int eb = blk - 28;
    const int ebid = ((eb & 7) << 7) | (eb >> 3);
    const int b = ebid >> 6, row = ebid & 63;
    const int lane = tid & 63, w = tid >> 6, quad = lane >> 4, nl = lane & 15;
    const int cp = tid >> 4, nq = tid & 15;

    // obs load issued early (used in phase X)
    const float4 x4 = *(const float4*)(obs + ((size_t)(b * 16 + cp) << 12) + row * 64 + nq * 4);

    // phase W: stage raw e1w (1024 f) + e2w (4096 f) into LDS, coalesced
    {
        float* wr = (float*)lds;
#pragma unroll
        for (int i = 0; i < 20; i++) {
            const int idx = tid + 256 * i;
            wr[idx] = (idx < 1024) ? e1w[idx] : e2w[idx - 1024];
        }
    }
    __syncthreads();

    // build this wave's weight fragments in registers (A-operand, M=feats)
    bf16x8 e1h, e1l, e2h[2], e2l[2];
    {
        const float* wr = (const float*)lds;
        const int f = 16 * w + nl;
#pragma unroll
        for (int j = 0; j < 8; j++) {
            const int k = quad * 8 + j;
            const float v = (k < 16) ? wr[k * 64 + f] : 0.f;
            ushort hi, lo; split_bf16(v, hi, lo);
            e1h[j] = (short)hi; e1l[j] = (short)lo;
        }
#pragma unroll
        for (int kc = 0; kc < 2; kc++)
#pragma unroll
            for (int j = 0; j < 8; j++) {
                const int k = kc * 32 + quad * 8 + j;
                const float v = wr[1024 + k * 64 + f];
                ushort hi, lo; split_bf16(v, hi, lo);
                e2h[kc][j] = (short)hi; e2l[kc][j] = (short)lo;
            }
    }
    __syncthreads();

    // phase X: stage obs packed (B-operand planes, k>=16 zeroed)
    unsigned* Xs = lds;
    unsigned* Hs = lds + 2080;
    {
        unsigned* xp = Xs + cp * 65 + nq * 4;
        xp[0] = pack_split(x4.x); xp[1] = pack_split(x4.y);
        xp[2] = pack_split(x4.z); xp[3] = pack_split(x4.w);
        unsigned* zp = Xs + (16 + cp) * 65 + nq * 4;
        zp[0] = 0u; zp[1] = 0u; zp[2] = 0u; zp[3] = 0u;
    }
    __syncthreads();

    // layer 1: wave w -> mid-feats 16w..16w+15
#pragma unroll
    for (int nt = 0; nt < 4; nt++) {
        const unsigned* bp = Xs + (quad * 8) * 65 + nt * 16 + nl;
        bf16x8 bh, bl; frag_packed(bp, bh, bl);
        f32x4 c = {0.f, 0.f, 0.f, 0.f};
        c = MFMA(e1h, bh, c); c = MFMA(e1h, bl, c); c = MFMA(e1l, bh, c);
#pragma unroll
        for (int reg = 0; reg < 4; reg++) {
            const int fm = 16 * w + quad * 4 + reg;
            Hs[fm * 65 + nt * 16 + nl] = pack_split(fmaxf(c[reg] + e1b[fm], 0.f));
        }
    }
    __syncthreads();

    // layer 2: K=64 (2 kc)
    f32x4 a2[4];
#pragma unroll
    for (int nt = 0; nt < 4; nt++) a2[nt] = (f32x4){0.f, 0.f, 0.f, 0.f};
#pragma unroll
    for (int kc = 0; kc < 2; kc++) {
#pragma unroll
        for (int nt = 0; nt < 4; nt++) {
            const unsigned* bp = Hs + (kc * 32 + quad * 8) * 65 + nt * 16 + nl;
            bf16x8 bh, bl; frag_packed(bp, bh, bl);
            a2[nt] = MFMA(e2h[kc], bh, a2[nt]);
            a2[nt] = MFMA(e2h[kc], bl, a2[nt]);
            a2[nt] = MFMA(e2l[kc], bh, a2[nt]);
        }
    }
#pragma unroll
    for (int reg = 0; reg < 4; reg++) {
        const int f = 16 * w + quad * 4 + reg;
        const float bv = e2b[f];
#pragma unroll
        for (int nt = 0; nt < 4; nt++)
            h0[((size_t)(b * 64 + f) << 12) + row * 64 + nt * 16 + nl] =
                fmaxf(a2[nt][reg] + bv, 0.f);
    }
}

// ---- GNN layer: quarter-pipelined, drain-free barriers, single S set ----
template <int K, bool MEAN>
__global__ __launch_bounds__(256, 4) void gnn_kernel(
    const float* __restrict__ hin, const ushort* __restrict__ wf,
    const float* __restrict__ bias, float* __restrict__ hout,
    float* __restrict__ gsum)
{
    constexpr int NQ = K / 32;            // quarters of 32 planes (= one kc each)
    __shared__ unsigned As[2][32 * 65];   // packed hi|lo, dbuf
    const int tid = threadIdx.x;
    // XCD-contiguous remap: consecutive rows on the same XCD (R7: FETCH 49->18MB)
    const int bid = ((blockIdx.x & 7) << 7) | (blockIdx.x >> 3);
    const int b = bid >> 6, row = bid & 63;
    const int lane = tid & 63, w = tid >> 6, quad = lane >> 4, nl = lane & 15;
    const int kp = tid >> 4, nq = tid & 15;
    const float* hb = hin + (size_t)b * K * 4096;
    const int rowu = (row > 0) ? row - 1 : row;
    const int rowd = (row < 63) ? row + 1 : row;
    const float su = (row > 0) ? 1.f : 0.f;
    const float sd = (row < 63) ? 1.f : 0.f;
    float inv[4];
#pragma unroll
    for (int i = 0; i < 4; i++) {
        const int n = nq * 4 + i;
        const int deg = (row > 0) + (row < 63) + (n > 0) + (n < 63);
        inv[i] = 1.f / ((float)deg + 1e-6f);
    }

    const ushort* wfl = wf + lane * 8;
    f32x4 acc[4][2];
#pragma unroll
    for (int nt = 0; nt < 4; nt++) {
        acc[nt][0] = (f32x4){0.f, 0.f, 0.f, 0.f};
        acc[nt][1] = (f32x4){0.f, 0.f, 0.f, 0.f};
    }

    float4 S[6];          // ONE staging register set (24 VGPR)
    bf16x8 V[2][2];       // current quarter's weights [ftl][hi/lo]

    auto sload = [&](int q) {
#pragma unroll
        for (int it = 0; it < 2; it++) {
            const int kg = q * 32 + it * 16 + kp;
            const float* pk = hb + ((size_t)kg << 12) + nq * 4;
            S[it * 3 + 0] = *(const float4*)(pk + row * 64);
            S[it * 3 + 1] = *(const float4*)(pk + rowu * 64);
            S[it * 3 + 2] = *(const float4*)(pk + rowd * 64);
        }
    };
    auto wload = [&](int q) {
#pragma unroll
        for (int ftl = 0; ftl < 2; ftl++) {
            V[ftl][0] = *(const bf16x8*)(wfl + ((q * 8 + 2 * w + ftl) * 2) * 512);
            V[ftl][1] = *(const bf16x8*)(wfl + ((q * 8 + 2 * w + ftl) * 2 + 1) * 512);
        }
    };
    auto stage = [&](unsigned* Ab) {
#pragma unroll
        for (int it = 0; it < 2; it++) {
            const int kl = it * 16 + kp;
            const float4 c4 = S[it * 3 + 0];
            const float4 u4 = S[it * 3 + 1];
            const float4 d4 = S[it * 3 + 2];
            const float pw = __shfl_up(c4.w, 1);
            const float nx = __shfl_down(c4.x, 1);
            const float lx = (nq > 0) ? pw : 0.f;
            const float rw = (nq < 15) ? nx : 0.f;
            unsigned* ap = Ab + kl * 65 + nq * 4;
            ap[0] = pack_split((su * u4.x + sd * d4.x + lx + c4.y) * inv[0]);
            ap[1] = pack_split((su * u4.y + sd * d4.y + c4.x + c4.z) * inv[1]);
            ap[2] = pack_split((su * u4.z + sd * d4.z + c4.y + c4.w) * inv[2]);
            ap[3] = pack_split((su * u4.w + sd * d4.w + c4.z + rw) * inv[3]);
        }
    };
    auto consume = [&](const unsigned* Ab) {
#pragma unroll
        for (int nt = 0; nt < 4; nt++) {
            const unsigned* bp = Ab + (quad * 8) * 65 + nt * 16 + nl;
            bf16x8 bh, bl; frag_packed(bp, bh, bl);
            acc[nt][0] = MFMA(V[0][0], bh, acc[nt][0]);
            acc[nt][0] = MFMA(V[0][0], bl, acc[nt][0]);
            acc[nt][0] = MFMA(V[0][1], bh, acc[nt][0]);
            acc[nt][1] = MFMA(V[1][0], bh, acc[nt][1]);
            acc[nt][1] = MFMA(V[1][0], bl, acc[nt][1]);
            acc[nt][1] = MFMA(V[1][1], bh, acc[nt][1]);
        }
    };

    // prologue
    wload(0);
    sload(0);
    stage(As[0]);              // drains prologue loads (once)
    sload(1);
    block_sync_lgkm();

#pragma unroll
    for (int q = 0; q < NQ; q++) {
        consume(As[q & 1]);                    // waits V(q): vmcnt<=6, no drain
        if (q + 1 < NQ) {
            wload(q + 1);
            stage(As[(q + 1) & 1]);            // waits S(q+1): vmcnt<=4
            if (q + 2 < NQ) sload(q + 2);      // S regs free after stage
            block_sync_lgkm();                 // globals stay in flight
        }
    }

    // ---- epilogue: + rowsum*bias, relu ----
    if (!MEAN) {
#pragma unroll
        for (int ftl = 0; ftl < 2; ftl++) {
            const int fb = 32 * w + 16 * ftl + quad * 4;
            const float b0 = bias[fb], b1 = bias[fb + 1], b2 = bias[fb + 2], b3 = bias[fb + 3];
#pragma unroll
            for (int nt = 0; nt < 4; nt++) {
                const int n = 16 * nt + nl;
                const int deg = (row > 0) + (row < 63) + (n > 0) + (n < 63);
                const float rs = (float)deg / ((float)deg + 1e-6f);
                float* op = hout + ((size_t)(b * 128 + fb) << 12) + row * 64 + n;
                op[0]        = fmaxf(acc[nt][ftl][0] + rs * b0, 0.f);
                op[1u << 12] = fmaxf(acc[nt][ftl][1] + rs * b1, 0.f);
                op[2u << 12] = fmaxf(acc[nt][ftl][2] + rs * b2, 0.f);
                op[3u << 12] = fmaxf(acc[nt][ftl][3] + rs * b3, 0.f);
            }
        }
    } else {
#pragma unroll
        for (int ftl = 0; ftl < 2; ftl++) {
            const int fb = 32 * w + 16 * ftl + quad * 4;
#pragma unroll
            for (int reg = 0; reg < 4; reg++) {
                const float bv = bias[fb + reg];
                float v = 0.f;
#pragma unroll
                for (int nt = 0; nt < 4; nt++) {
                    const int n = 16 * nt + nl;
                    const int deg = (row > 0) + (row < 63) + (n > 0) + (n < 63);
                    const float rs = (float)deg / ((float)deg + 1e-6f);
                    v += fmaxf(acc[nt][ftl][reg] + rs * bv, 0.f);
                }
                v += __shfl_xor(v, 1); v += __shfl_xor(v, 2);
                v += __shfl_xor(v, 4); v += __shfl_xor(v, 8);
                if (nl == 0) atomicAdd(&gsum[b * 128 + fb + reg], v * (1.f / 4096.f));
            }
        }
    }
}

// ---- readout: per-batch block, 2-layer MLP (fp32 vector) ----
__global__ __launch_bounds__(256) void readout_kernel(
    const float* __restrict__ gsum, const float* __restrict__ r1w,
    const float* __restrict__ r1b, const float* __restrict__ r2w,
    const float* __restrict__ r2b, float* __restrict__ out)
{
    __shared__ float gs[128];
    __shared__ float g2[256];
    const int b = blockIdx.x, tid = threadIdx.x;
    if (tid < 128) gs[tid] = gsum[b * 128 + tid];
    __syncthreads();
    float a = r1b[tid];
#pragma unroll 16
    for (int k = 0; k < 128; k++) a = fmaf(gs[k], r1w[k * 256 + tid], a);
    g2[tid] = fmaxf(a, 0.f);
    __syncthreads();
    float a2 = r2b[tid];
#pragma unroll 16
    for (int k = 0; k < 256; k++) a2 = fmaf(g2[k], r2w[k * 256 + tid], a2);
    out[b * 256 + tid] = fmaxf(a2, 0.f);
}

extern "C" void kernel_launch(void* const* d_in, const int* in_sizes, int n_in,
                              void* d_out, int out_size, void* d_ws, size_t ws_size,
                              hipStream_t stream)
{
    const float* obs = (const float*)d_in[0];
    const float* e1w = (const float*)d_in[1];
    const float* e1b = (const float*)d_in[2];
    const float* e2w = (const float*)d_in[3];
    const float* e2b = (const float*)d_in[4];
    const float* g1w = (const float*)d_in[5];
    const float* g1b = (const float*)d_in[6];
    const float* g2w = (const float*)d_in[7];
    const float* g2b = (const float*)d_in[8];
    const float* g3w = (const float*)d_in[9];
    const float* g3b = (const float*)d_in[10];
    const float* r1w = (const float*)d_in[11];
    const float* r1b = (const float*)d_in[12];
    const float* r2w = (const float*)d_in[13];
    const float* r2b = (const float*)d_in[14];
    float* out = (float*)d_out;
    float* ws = (float*)d_ws;

    float* h0 = ws;                                   // 16 MB
    float* h1 = ws + 4194304;                         // 32 MB
    float* h2 = ws + 4194304 + 8388608;               // 32 MB
    float* gsum = (float*)((char*)d_ws + 80u * 1024u * 1024u);          // 8 KB
    ushort* wfb = (ushort*)((char*)d_ws + 80u * 1024u * 1024u + 8192u); // 184 KB

    hipLaunchKernelGGL(prep_embed_kernel, dim3(1052), dim3(256), 0, stream,
                       obs, e1w, e1b, e2w, e2b, g1w, g2w, g3w, wfb, gsum, h0);
    hipLaunchKernelGGL((gnn_kernel<64, false>), dim3(1024), dim3(256), 0, stream,
                       h0, wfb + 12288, g1b, h1, nullptr);
    hipLaunchKernelGGL((gnn_kernel<128, false>), dim3(1024), dim3(256), 0, stream,
                       h1, wfb + 28672, g2b, h2, nullptr);
    hipLaunchKernelGGL((gnn_kernel<128, true>), dim3(1024), dim3(256), 0, stream,
                       h2, wfb + 61440, g3b, nullptr, gsum);
    hipLaunchKernelGGL(readout_kernel, dim3(16), dim3(256), 0, stream,
                       gsum, r1w, r1b, r2w, r2b, out);
}